// Round 1
// baseline (266.414 us; speedup 1.0000x reference)
//
#include <hip/hip_runtime.h>

#define BB 2
#define DD 160
#define HH 192
#define WW 160
#define HWs (HH * WW)          // 30720
#define NTOT 9830400.0f        // 2*160*192*160

__device__ __forceinline__ float4 f4z() { return make_float4(0.f, 0.f, 0.f, 0.f); }
__device__ __forceinline__ float4 f4add(float4 a, float4 b) {
    return make_float4(a.x + b.x, a.y + b.y, a.z + b.z, a.w + b.w);
}
__device__ __forceinline__ float4 f4fma(float4 a, float4 b, float4 c) {
    return make_float4(fmaf(a.x, b.x, c.x), fmaf(a.y, b.y, c.y),
                       fmaf(a.z, b.z, c.z), fmaf(a.w, b.w, c.w));
}

// K1: fused W+H 9x9 box-SUM of 5 channels {I, J, I*I, J*J, I*J} for one d-slice
// tile (32x32 outputs). Zero padding at H/W borders (matches 'SAME' conv).
// Output layout: ws5[c][b][slot][h][w], slot = s - s_base.
__global__ __launch_bounds__(256) void k1_hw(const float* __restrict__ I,
                                             const float* __restrict__ J,
                                             float* __restrict__ ws5,
                                             int s_base, int nslices) {
    __shared__ float rawI[40][48];     // rows h0-4..h0+35, cols w0-8..w0+39
    __shared__ float rawJ[40][48];
    __shared__ float hs[5][32][44];    // H-filtered, cols w0-4..w0+35 (pad to 44)

    const int tid  = threadIdx.x;
    const int slot = blockIdx.y;
    const int s    = s_base + slot;
    if (s < 0 || s >= DD) return;      // halo slot outside volume; K2 zeros these
    const int b  = blockIdx.z;
    const int tx = blockIdx.x % 5;     // W/32 = 5 tiles
    const int ty = blockIdx.x / 5;     // H/32 = 6 tiles
    const int w0 = tx * 32, h0 = ty * 32;

    const size_t sbase = (size_t)(b * DD + s) * HWs;
    const float* Ip = I + sbase;
    const float* Jp = J + sbase;

    // ---- stage raw tile (float4; gw is always 4-aligned, W%4==0 -> full-or-zero)
    for (int idx = tid; idx < 480; idx += 256) {
        int row = idx / 12, g = idx % 12;
        int gh = h0 - 4 + row;
        int gw = w0 - 8 + g * 4;
        float4 vi = f4z(), vj = f4z();
        if (gh >= 0 && gh < HH && gw >= 0 && gw + 3 < WW) {
            vi = *(const float4*)(Ip + (size_t)gh * WW + gw);
            vj = *(const float4*)(Jp + (size_t)gh * WW + gw);
        }
        *(float4*)&rawI[row][g * 4] = vi;
        *(float4*)&rawJ[row][g * 4] = vj;
    }
    __syncthreads();

    // ---- H pass: 9-tap vertical sums for rows h0..h0+31, cols w0-4..w0+35
    for (int idx = tid; idx < 320; idx += 256) {
        int r = idx / 10, k = idx % 10;
        float4 sI = f4z(), sJ = f4z(), sII = f4z(), sJJ = f4z(), sIJ = f4z();
#pragma unroll
        for (int t = 0; t < 9; ++t) {
            float4 a  = *(const float4*)&rawI[r + t][4 + k * 4];
            float4 bb = *(const float4*)&rawJ[r + t][4 + k * 4];
            sI  = f4add(sI, a);
            sJ  = f4add(sJ, bb);
            sII = f4fma(a, a, sII);
            sJJ = f4fma(bb, bb, sJJ);
            sIJ = f4fma(a, bb, sIJ);
        }
        *(float4*)&hs[0][r][k * 4] = sI;
        *(float4*)&hs[1][r][k * 4] = sJ;
        *(float4*)&hs[2][r][k * 4] = sII;
        *(float4*)&hs[3][r][k * 4] = sJJ;
        *(float4*)&hs[4][r][k * 4] = sIJ;
    }
    __syncthreads();

    // ---- W pass: 9-tap horizontal (sliding over 4 outputs), write to global
    {
        const int r = tid >> 3, g = tid & 7;
        const size_t chanStride = (size_t)BB * nslices * HWs;
        const size_t obase =
            ((size_t)(b * nslices + slot) * HH + (h0 + r)) * WW + (w0 + g * 4);
#pragma unroll
        for (int c = 0; c < 5; ++c) {
            const float* hp = &hs[c][r][g * 4];
            float4 v0 = *(const float4*)hp;
            float4 v1 = *(const float4*)(hp + 4);
            float4 v2 = *(const float4*)(hp + 8);
            float o0 = v0.x + v0.y + v0.z + v0.w + v1.x + v1.y + v1.z + v1.w + v2.x;
            float o1 = o0 - v0.x + v2.y;
            float o2 = o1 - v0.y + v2.z;
            float o3 = o2 - v0.z + v2.w;
            *(float4*)(ws5 + c * chanStride + obase) = make_float4(o0, o1, o2, o3);
        }
    }
}

// K2: sliding 9-window along D over the 5 HW-summed channels; per-voxel cc;
// block-reduced partial sums atomically accumulated into *partial.
// The "leaving" window value is re-read from global (9 slices behind -> L2 hit).
__global__ __launch_bounds__(256) void k2_d(const float* __restrict__ ws5,
                                            float* __restrict__ partial,
                                            int c0, int dn, int nslices) {
    const int tid = threadIdx.x;
    const int col = blockIdx.x * 256 + tid;   // 61440 columns total
    const int w  = col % WW;
    const int t1 = col / WW;
    const int h  = t1 % HH;
    const int b  = t1 / HH;
    const size_t chanStride = (size_t)BB * nslices * HWs;
    size_t idx = ((size_t)b * nslices * HH + h) * WW + w;   // slot 0

    float S0 = 0.f, S1 = 0.f, S2 = 0.f, S3 = 0.f, S4 = 0.f, acc = 0.f;
    const int T = dn + 8;
    const float inv = 1.0f / 729.0f;
    for (int t = 0; t < T; ++t, idx += HWs) {
        const int si = c0 - 4 + t;
        float x0 = 0.f, x1 = 0.f, x2 = 0.f, x3 = 0.f, x4 = 0.f;
        if (si >= 0 && si < DD) {
            const float* p = ws5 + idx;
            x0 = p[0];
            x1 = p[chanStride];
            x2 = p[2 * chanStride];
            x3 = p[3 * chanStride];
            x4 = p[4 * chanStride];
        }
        float y0 = 0.f, y1 = 0.f, y2 = 0.f, y3 = 0.f, y4 = 0.f;
        if (t >= 9 && si - 9 >= 0) {
            const float* q = ws5 + idx - (size_t)9 * HWs;
            y0 = q[0];
            y1 = q[chanStride];
            y2 = q[2 * chanStride];
            y3 = q[3 * chanStride];
            y4 = q[4 * chanStride];
        }
        S0 += x0 - y0; S1 += x1 - y1; S2 += x2 - y2; S3 += x3 - y3; S4 += x4 - y4;
        if (t >= 8) {  // output depth d = si - 4 is valid
            float mu1 = S0 * inv, mu2 = S1 * inv;
            float g1  = fmaf(-mu1, mu1, S2 * inv);   // sigma1_sq
            float g2  = fmaf(-mu2, mu2, S3 * inv);   // sigma2_sq
            float g12 = fmaf(-mu1, mu2, S4 * inv);   // sigma12
            acc += __fdividef(g12 * g12, fmaf(g1, g2, 1e-5f));
        }
    }

    __shared__ float red[256];
    red[tid] = acc;
    __syncthreads();
    for (int off = 128; off > 0; off >>= 1) {
        if (tid < off) red[tid] += red[tid + off];
        __syncthreads();
    }
    if (tid == 0) atomicAdd(partial, red[0]);
}

__global__ void k3_final(const float* __restrict__ partial, float* __restrict__ out) {
    if (threadIdx.x == 0) out[0] = -partial[0] * (1.0f / NTOT);
}

extern "C" void kernel_launch(void* const* d_in, const int* in_sizes, int n_in,
                              void* d_out, int out_size, void* d_ws, size_t ws_size,
                              hipStream_t stream) {
    (void)in_sizes; (void)n_in; (void)out_size;
    const float* I = (const float*)d_in[0];   // y_true
    const float* J = (const float*)d_in[1];   // y_pred
    float* out     = (float*)d_out;
    float* partial = (float*)d_ws;            // 1 float accumulator
    float* data    = (float*)((char*)d_ws + 256);

    // Per-slice footprint for 5 channels x 2 batches: 5*2*H*W*4 bytes
    const size_t perSlice = (size_t)5 * BB * HWs * 4;   // 1,228,800 B
    size_t avail = (ws_size > 256) ? ws_size - 256 : 0;
    int maxNs = (int)(avail / perSlice);
    int Dc = maxNs - 8;                 // output slices per chunk
    if (Dc > DD) Dc = DD;
    if (Dc < 1)  Dc = 1;                // (assumes ws_size >= ~11 MB)
    const int nchunks = (DD + Dc - 1) / Dc;

    hipMemsetAsync(partial, 0, sizeof(float), stream);

    for (int c = 0; c < nchunks; ++c) {
        const int c0 = c * Dc;
        const int dn = (c0 + Dc <= DD) ? Dc : (DD - c0);
        const int nslices = dn + 8;
        const int s_base  = c0 - 4;
        dim3 g1(30, nslices, BB);       // 6x5 tiles per slice
        k1_hw<<<g1, 256, 0, stream>>>(I, J, data, s_base, nslices);
        k2_d<<<240, 256, 0, stream>>>(data, partial, c0, dn, nslices);
    }
    k3_final<<<1, 64, 0, stream>>>(partial, out);
}

// Round 3
// 213.756 us; speedup vs baseline: 1.2463x; 1.2463x over previous
//
#include <hip/hip_runtime.h>

#define BB 2
#define DD 160
#define HH 192
#define WW 160
#define HWs (HH * WW)          // 30720
#define NTOT 9830400.0f        // 2*160*192*160
#define NS 6                   // slices per k1 block
#define DSEG 20                // output slices per k2 segment

typedef float v4 __attribute__((ext_vector_type(4)));

__device__ __forceinline__ float4 f4z() { return make_float4(0.f, 0.f, 0.f, 0.f); }
__device__ __forceinline__ float4 f4add(float4 a, float4 b) {
    return make_float4(a.x + b.x, a.y + b.y, a.z + b.z, a.w + b.w);
}
__device__ __forceinline__ float4 f4fma(float4 a, float4 b, float4 c) {
    return make_float4(fmaf(a.x, b.x, c.x), fmaf(a.y, b.y, c.y),
                       fmaf(a.z, b.z, c.z), fmaf(a.w, b.w, c.w));
}

// K1: fused W+H 9x9 box-SUM of 5 channels {I, J, I*I, J*J, I*J}.
// Each block: one 32x32 (h,w) tile, NS consecutive slices, with the next
// slice's raw tile prefetched into registers while H/W passes run.
// Output layout: ws5[c][b][slot][h][w], slot = s - s_base.
__global__ __launch_bounds__(256) void k1_hw(const float* __restrict__ I,
                                             const float* __restrict__ J,
                                             float* __restrict__ ws5,
                                             int s_base, int nslices) {
    __shared__ float rawI[40][48];     // rows h0-4..h0+35, cols w0-8..w0+39
    __shared__ float rawJ[40][48];
    __shared__ float hs[5][32][44];    // H-filtered, cols w0-4..w0+35 (pad 44)

    const int tid = threadIdx.x;
    const int b   = blockIdx.z;
    const int tx  = blockIdx.x % 5;    // W/32 = 5 tiles
    const int ty  = blockIdx.x / 5;    // H/32 = 6 tiles
    const int w0 = tx * 32, h0 = ty * 32;

    const int sl0 = blockIdx.y * NS;         // first slot of this block
    const int nsl = min(NS, nslices - sl0);  // slots handled here
    if (nsl <= 0) return;

    // per-thread staging slots: idx = tid and tid+256 (covers 480 f4 rows)
    const int row0 = tid / 12,         g0 = tid % 12;
    const int row1 = (tid + 256) / 12, g1 = (tid + 256) % 12;
    const int gh0 = h0 - 4 + row0, gw0 = w0 - 8 + g0 * 4;
    const int gh1 = h0 - 4 + row1, gw1 = w0 - 8 + g1 * 4;
    const bool ok0 = (gh0 >= 0 && gh0 < HH && gw0 >= 0 && gw0 + 3 < WW);
    const bool ok1 = (tid < 224) && (gh1 >= 0 && gh1 < HH && gw1 >= 0 && gw1 + 3 < WW);
    const size_t off0 = (size_t)gh0 * WW + gw0;
    const size_t off1 = (size_t)gh1 * WW + gw1;

    float4 pI0, pJ0, pI1, pJ1;

    // preload first slice of this block
    {
        const int s = s_base + sl0;
        const bool sv = (s >= 0 && s < DD);
        const size_t sb = (size_t)(b * DD + s) * HWs;
        pI0 = (sv && ok0) ? *(const float4*)(I + sb + off0) : f4z();
        pJ0 = (sv && ok0) ? *(const float4*)(J + sb + off0) : f4z();
        pI1 = (sv && ok1) ? *(const float4*)(I + sb + off1) : f4z();
        pJ1 = (sv && ok1) ? *(const float4*)(J + sb + off1) : f4z();
    }

    const size_t chanStride = (size_t)BB * nslices * HWs;
    const int wr = tid >> 3, wg = tid & 7;   // W-pass mapping: 32 rows x 8 f4

    for (int j = 0; j < nsl; ++j) {
        const int slot = sl0 + j;
        const int s    = s_base + slot;

        // stage current slice regs -> LDS
        *(float4*)&rawI[row0][g0 * 4] = pI0;
        *(float4*)&rawJ[row0][g0 * 4] = pJ0;
        if (tid < 224) {
            *(float4*)&rawI[row1][g1 * 4] = pI1;
            *(float4*)&rawJ[row1][g1 * 4] = pJ1;
        }
        __syncthreads();

        // prefetch next slice into regs (latency hidden behind H+W passes)
        if (j + 1 < nsl) {
            const int sn = s + 1;
            const bool sv = (sn >= 0 && sn < DD);
            const size_t sb = (size_t)(b * DD + sn) * HWs;
            pI0 = (sv && ok0) ? *(const float4*)(I + sb + off0) : f4z();
            pJ0 = (sv && ok0) ? *(const float4*)(J + sb + off0) : f4z();
            pI1 = (sv && ok1) ? *(const float4*)(I + sb + off1) : f4z();
            pJ1 = (sv && ok1) ? *(const float4*)(J + sb + off1) : f4z();
        }

        // H pass: 9-tap vertical sums, rows h0..h0+31, cols w0-4..w0+35
        for (int idx = tid; idx < 320; idx += 256) {
            int r = idx / 10, k = idx % 10;
            float4 sI = f4z(), sJ = f4z(), sII = f4z(), sJJ = f4z(), sIJ = f4z();
#pragma unroll
            for (int t = 0; t < 9; ++t) {
                float4 a  = *(const float4*)&rawI[r + t][4 + k * 4];
                float4 bb = *(const float4*)&rawJ[r + t][4 + k * 4];
                sI  = f4add(sI, a);
                sJ  = f4add(sJ, bb);
                sII = f4fma(a, a, sII);
                sJJ = f4fma(bb, bb, sJJ);
                sIJ = f4fma(bb, a, sIJ);
            }
            *(float4*)&hs[0][r][k * 4] = sI;
            *(float4*)&hs[1][r][k * 4] = sJ;
            *(float4*)&hs[2][r][k * 4] = sII;
            *(float4*)&hs[3][r][k * 4] = sJJ;
            *(float4*)&hs[4][r][k * 4] = sIJ;
        }
        __syncthreads();

        // W pass: 9-tap horizontal sliding, store to global.
        if (s >= 0 && s < DD) {
            const size_t obase =
                ((size_t)(b * nslices + slot) * HH + (h0 + wr)) * WW + (w0 + wg * 4);
#pragma unroll
            for (int c = 0; c < 5; ++c) {
                const float* hp = &hs[c][wr][wg * 4];
                float4 v0 = *(const float4*)hp;
                float4 v1 = *(const float4*)(hp + 4);
                float4 v2 = *(const float4*)(hp + 8);
                float o0 = v0.x + v0.y + v0.z + v0.w + v1.x + v1.y + v1.z + v1.w + v2.x;
                float o1 = o0 - v0.x + v2.y;
                float o2 = o1 - v0.y + v2.z;
                float o3 = o2 - v0.z + v2.w;
                *(float4*)(ws5 + c * chanStride + obase) = make_float4(o0, o1, o2, o3);
            }
        }
        __syncthreads();
    }
}

// K2: sliding 9-window along D; 4 w-columns per thread via ext_vector_type
// (legal [] element access — float4 member-pointer indexing is UB and was
// the round-2 miscompile). D split into segments via blockIdx.y.
__global__ __launch_bounds__(256) void k2_d(const float* __restrict__ ws5,
                                            float* __restrict__ partial,
                                            int c0, int dn, int nslices) {
    const int tid = threadIdx.x;
    const int q   = blockIdx.x * 256 + tid;    // f4-column id, 15360 total
    const int w4  = q % 40;
    const int t1  = q / 40;
    const int h   = t1 % HH;
    const int b   = t1 / HH;

    const int d0    = c0 + blockIdx.y * DSEG;          // segment output start
    const int dnseg = min(DSEG, c0 + dn - d0);
    if (dnseg <= 0) return;

    const size_t cs = (size_t)BB * nslices * HWs;      // channel stride
    const int slot0 = d0 - c0;                          // slot of si = d0-4
    size_t idx = ((size_t)(b * nslices + slot0) * HH + h) * WW + w4 * 4;

    v4 S0 = 0.f, S1 = 0.f, S2 = 0.f, S3 = 0.f, S4 = 0.f, acc = 0.f;
    const int T = dnseg + 8;
    const float inv = 1.0f / 729.0f;
    for (int t = 0; t < T; ++t, idx += HWs) {
        const int si = d0 - 4 + t;
        v4 x0 = 0.f, x1 = 0.f, x2 = 0.f, x3 = 0.f, x4 = 0.f;
        if (si >= 0 && si < DD) {
            const float* p = ws5 + idx;
            x0 = *(const v4*)(p);
            x1 = *(const v4*)(p + cs);
            x2 = *(const v4*)(p + 2 * cs);
            x3 = *(const v4*)(p + 3 * cs);
            x4 = *(const v4*)(p + 4 * cs);
        }
        if (t >= 9 && si - 9 >= 0) {
            const float* qq = ws5 + idx - (size_t)9 * HWs;
            x0 -= *(const v4*)(qq);
            x1 -= *(const v4*)(qq + cs);
            x2 -= *(const v4*)(qq + 2 * cs);
            x3 -= *(const v4*)(qq + 3 * cs);
            x4 -= *(const v4*)(qq + 4 * cs);
        }
        S0 += x0; S1 += x1; S2 += x2; S3 += x3; S4 += x4;
        if (t >= 8) {  // output depth d = si - 4 is valid
            v4 mu1 = S0 * inv, mu2 = S1 * inv;
            v4 g1  = S2 * inv - mu1 * mu1;   // sigma1_sq
            v4 g2  = S3 * inv - mu2 * mu2;   // sigma2_sq
            v4 g12 = S4 * inv - mu1 * mu2;   // sigma12
            v4 num = g12 * g12;
            v4 den = g1 * g2 + 1e-5f;
#pragma unroll
            for (int e = 0; e < 4; ++e)
                acc[e] += __fdividef(num[e], den[e]);
        }
    }

    __shared__ float red[256];
    red[tid] = acc[0] + acc[1] + acc[2] + acc[3];
    __syncthreads();
    for (int off = 128; off > 0; off >>= 1) {
        if (tid < off) red[tid] += red[tid + off];
        __syncthreads();
    }
    if (tid == 0) atomicAdd(partial, red[0]);
}

__global__ void k3_final(const float* __restrict__ partial, float* __restrict__ out) {
    if (threadIdx.x == 0) out[0] = -partial[0] * (1.0f / NTOT);
}

extern "C" void kernel_launch(void* const* d_in, const int* in_sizes, int n_in,
                              void* d_out, int out_size, void* d_ws, size_t ws_size,
                              hipStream_t stream) {
    (void)in_sizes; (void)n_in; (void)out_size;
    const float* I = (const float*)d_in[0];   // y_true
    const float* J = (const float*)d_in[1];   // y_pred
    float* out     = (float*)d_out;
    float* partial = (float*)d_ws;            // 1 float accumulator
    float* data    = (float*)((char*)d_ws + 256);

    const size_t perSlice = (size_t)5 * BB * HWs * 4;   // 1,228,800 B
    size_t avail = (ws_size > 256) ? ws_size - 256 : 0;
    int maxNs = (int)(avail / perSlice);
    int Dc = maxNs - 8;                 // output slices per chunk
    if (Dc > DD) Dc = DD;
    if (Dc < 1)  Dc = 1;
    const int nchunks = (DD + Dc - 1) / Dc;

    hipMemsetAsync(partial, 0, sizeof(float), stream);

    for (int c = 0; c < nchunks; ++c) {
        const int c0 = c * Dc;
        const int dn = (c0 + Dc <= DD) ? Dc : (DD - c0);
        const int nslices = dn + 8;
        const int s_base  = c0 - 4;
        dim3 g1(30, (nslices + NS - 1) / NS, BB);
        k1_hw<<<g1, 256, 0, stream>>>(I, J, data, s_base, nslices);
        dim3 g2(60, (dn + DSEG - 1) / DSEG, 1);
        k2_d<<<g2, 256, 0, stream>>>(data, partial, c0, dn, nslices);
    }
    k3_final<<<1, 64, 0, stream>>>(partial, out);
}

// Round 4
// 181.969 us; speedup vs baseline: 1.4641x; 1.1747x over previous
//
#include <hip/hip_runtime.h>

#define DD 160
#define HH 192
#define WW 160
#define HWs (HH * WW)           // 30720
#define NTOT 9830400.0f        // 2*160*192*160
#define TH 16                  // tile height (h)
#define TW 32                  // tile width (w)
#define DOUT 40                // output slices per block (160/4)
#define NIT 48                 // DOUT + 8 halo slices

typedef float    v4 __attribute__((ext_vector_type(4)));
typedef _Float16 h4 __attribute__((ext_vector_type(4)));

// Fully-fused NCC: per block one 32(w)x16(h) tile and a 40-slice D-range.
// Pipeline per input slice si: stage raw I/J tile -> LDS, 9-tap H pass -> hs,
// 9-tap sliding W pass -> per-thread f4 of 5 HW-sums, pushed into a 9-slot
// fp16 ring (LDS) driving rolling D-sums in registers; cc epilogue per output
// slice. Intermediate never touches HBM (round-3 k1 wrote 196 MB + k2 re-read).
// fp16 ring: rolling add/sub uses the identical fp16 value -> drift cancels
// exactly; rounding error ~9e-5 on sigma terms, final mean err ~2e-5.
__global__ __launch_bounds__(256, 2) void kf(const float* __restrict__ I,
                                             const float* __restrict__ J,
                                             float* __restrict__ partial) {
    // strides padded to 44 (=12 mod 32): bank group (3r+k)%8 near-uniform.
    __shared__ float rawI[24][44];          // rows h0-4..h0+19, cols w0-4..w0+35
    __shared__ float rawJ[24][44];
    __shared__ float hs[5][16][44];         // H-filtered, cols w0-4..w0+35
    __shared__ h4    ring[9][5][128];       // [slot][chan][f4-group], 46080 B
    __shared__ float red[256];

    const int tid = threadIdx.x;
    const int b   = blockIdx.z;
    const int tx  = blockIdx.x % 5;         // 5 w-tiles
    const int ty  = blockIdx.x / 5;         // 12 h-tiles
    const int w0 = tx * TW, h0 = ty * TH;
    const int d0 = blockIdx.y * DOUT;

    // ---- staging task decode: 480 f4-tasks (0..239 -> I, 240..479 -> J)
    // taskA = tid, taskB = tid+256 (valid for tid<224)
    const int uA = (tid < 240) ? tid : tid - 240;
    const int rA = uA / 10, gA = uA % 10;
    const int ghA = h0 - 4 + rA, gwA = w0 - 4 + gA * 4;
    const bool okA = (ghA >= 0 && ghA < HH && gwA >= 0 && gwA < WW);
    const float* srcA = (tid < 240) ? I : J;
    float* dstA = (tid < 240) ? &rawI[rA][gA * 4] : &rawJ[rA][gA * 4];
    const size_t offA = (size_t)ghA * WW + gwA;

    const int tB = tid + 256;               // 256..479 -> always J
    const int uB = tB - 240;
    const int rB = uB / 10, gB = uB % 10;
    const int ghB = h0 - 4 + rB, gwB = w0 - 4 + gB * 4;
    const bool okB = (tid < 224) && (ghB >= 0 && ghB < HH && gwB >= 0 && gwB < WW);
    float* dstB = &rawJ[rB][gB * 4];
    const size_t offB = (size_t)ghB * WW + gwB;

    const size_t base_b = (size_t)b * DD * HWs;
    const v4 z4 = (v4)0.f;
    float4 pA = make_float4(0, 0, 0, 0), pB = make_float4(0, 0, 0, 0);

    // preload first slice if valid (d0>0 blocks; d0==0 starts with ghosts)
    {
        const int si0 = d0 - 4;
        if (si0 >= 0) {
            const size_t sb = base_b + (size_t)si0 * HWs;
            pA = okA ? *(const float4*)(srcA + sb + offA) : make_float4(0, 0, 0, 0);
            pB = okB ? *(const float4*)(J + sb + offB)    : make_float4(0, 0, 0, 0);
        }
    }

    // W-pass / epilogue mapping (tid < 128): f4-group tid = (wr, wg)
    const int wr = tid >> 3, wg = tid & 7;
    v4 S0 = z4, S1 = z4, S2 = z4, S3 = z4, S4 = z4, acc = z4;
    const float inv = 1.0f / 729.0f;

    for (int t = 0; t < NIT; ++t) {
        const int si = d0 - 4 + t;
        const bool sv = (si >= 0 && si < DD);   // block-uniform

        if (sv) {   // stage regs -> LDS
            *(float4*)dstA = pA;
            if (tid < 224) *(float4*)dstB = pB;
            __syncthreads();
        }

        // prefetch next slice (latency hidden behind H/W passes)
        {
            const int sn = si + 1;
            if (t + 1 < NIT && sn >= 0 && sn < DD) {
                const size_t sb = base_b + (size_t)sn * HWs;
                pA = okA ? *(const float4*)(srcA + sb + offA) : make_float4(0, 0, 0, 0);
                pB = okB ? *(const float4*)(J + sb + offB)    : make_float4(0, 0, 0, 0);
            }
        }

        if (sv) {   // H pass: 160 tasks = 16 rows x 10 f4-cols
            if (tid < 160) {
                const int r = tid / 10, k = tid % 10;
                v4 sI = z4, sJ = z4, sII = z4, sJJ = z4, sIJ = z4;
#pragma unroll
                for (int tt = 0; tt < 9; ++tt) {
                    v4 a  = *(const v4*)&rawI[r + tt][4 * k];
                    v4 bb = *(const v4*)&rawJ[r + tt][4 * k];
                    sI += a; sJ += bb; sII += a * a; sJJ += bb * bb; sIJ += a * bb;
                }
                *(v4*)&hs[0][r][4 * k] = sI;
                *(v4*)&hs[1][r][4 * k] = sJ;
                *(v4*)&hs[2][r][4 * k] = sII;
                *(v4*)&hs[3][r][4 * k] = sJJ;
                *(v4*)&hs[4][r][4 * k] = sIJ;
            }
            __syncthreads();
        }

        if (tid < 128) {
            // W pass: sliding 9-tap over hs -> h[5] (f4 of HW-sums)
            v4 h[5];
            if (sv) {
#pragma unroll
                for (int c = 0; c < 5; ++c) {
                    const float* hp = &hs[c][wr][wg * 4];
                    v4 a0 = *(const v4*)hp;
                    v4 a1 = *(const v4*)(hp + 4);
                    v4 a2 = *(const v4*)(hp + 8);
                    float o0 = a0.x + a0.y + a0.z + a0.w +
                               a1.x + a1.y + a1.z + a1.w + a2.x;
                    float o1 = o0 - a0.x + a2.y;
                    float o2 = o1 - a0.y + a2.z;
                    float o3 = o2 - a0.z + a2.w;
                    v4 hv; hv.x = o0; hv.y = o1; hv.z = o2; hv.w = o3;
                    h[c] = hv;
                }
            } else {
#pragma unroll
                for (int c = 0; c < 5; ++c) h[c] = z4;
            }

            // ring rotate + rolling D-sum (read old BEFORE overwrite; same
            // thread owns the address -> no barrier needed)
            const int slot = t % 9;
            h4 n0 = __builtin_convertvector(h[0], h4);
            h4 n1 = __builtin_convertvector(h[1], h4);
            h4 n2 = __builtin_convertvector(h[2], h4);
            h4 n3 = __builtin_convertvector(h[3], h4);
            h4 n4 = __builtin_convertvector(h[4], h4);
            if (t >= 9) {
                S0 -= __builtin_convertvector(ring[slot][0][tid], v4);
                S1 -= __builtin_convertvector(ring[slot][1][tid], v4);
                S2 -= __builtin_convertvector(ring[slot][2][tid], v4);
                S3 -= __builtin_convertvector(ring[slot][3][tid], v4);
                S4 -= __builtin_convertvector(ring[slot][4][tid], v4);
            }
            ring[slot][0][tid] = n0;
            ring[slot][1][tid] = n1;
            ring[slot][2][tid] = n2;
            ring[slot][3][tid] = n3;
            ring[slot][4][tid] = n4;
            S0 += __builtin_convertvector(n0, v4);
            S1 += __builtin_convertvector(n1, v4);
            S2 += __builtin_convertvector(n2, v4);
            S3 += __builtin_convertvector(n3, v4);
            S4 += __builtin_convertvector(n4, v4);

            if (t >= 8) {   // output depth d = si-4 in [d0, d0+39]
                v4 mu1 = S0 * inv, mu2 = S1 * inv;
                v4 g1  = S2 * inv - mu1 * mu1;
                v4 g2  = S3 * inv - mu2 * mu2;
                v4 g12 = S4 * inv - mu1 * mu2;
                v4 num = g12 * g12;
                v4 den = g1 * g2 + 1e-5f;
#pragma unroll
                for (int e = 0; e < 4; ++e)
                    acc[e] += __fdividef(num[e], den[e]);
            }
        }

        if (sv) __syncthreads();   // protect raw/hs before next stage/H write
    }

    red[tid] = (tid < 128) ? (acc[0] + acc[1] + acc[2] + acc[3]) : 0.f;
    __syncthreads();
    for (int off = 128; off > 0; off >>= 1) {
        if (tid < off) red[tid] += red[tid + off];
        __syncthreads();
    }
    if (tid == 0) atomicAdd(partial, red[0]);
}

__global__ void k3_final(const float* __restrict__ partial, float* __restrict__ out) {
    if (threadIdx.x == 0) out[0] = -partial[0] * (1.0f / NTOT);
}

extern "C" void kernel_launch(void* const* d_in, const int* in_sizes, int n_in,
                              void* d_out, int out_size, void* d_ws, size_t ws_size,
                              hipStream_t stream) {
    (void)in_sizes; (void)n_in; (void)out_size; (void)ws_size;
    const float* I = (const float*)d_in[0];   // y_true
    const float* J = (const float*)d_in[1];   // y_pred
    float* out     = (float*)d_out;
    float* partial = (float*)d_ws;            // 1 float accumulator

    hipMemsetAsync(partial, 0, sizeof(float), stream);
    dim3 grid(60, 4, 2);                      // (5 w-tiles x 12 h-tiles, D/40, B)
    kf<<<grid, 256, 0, stream>>>(I, J, partial);
    k3_final<<<1, 64, 0, stream>>>(partial, out);
}

// Round 5
// 163.533 us; speedup vs baseline: 1.6291x; 1.1127x over previous
//
#include <hip/hip_runtime.h>

#define DD 160
#define HH 192
#define WW 160
#define HWs (HH * WW)          // 30720
#define NTOT 9830400.0f        // 2*160*192*160
#define DOUT 40                // output slices per block
#define NIT  48                // DOUT + 8 halo
#define NBLK 480

typedef float    v4 __attribute__((ext_vector_type(4)));
typedef float    v8 __attribute__((ext_vector_type(8)));
typedef _Float16 h4 __attribute__((ext_vector_type(4)));
typedef _Float16 h8 __attribute__((ext_vector_type(8)));

// Fully-fused NCC, software-pipelined: per block one 32(w)x16(h) tile x 40
// output slices. Per iteration t (one input slice): stage prefetched regs ->
// raw[t&1]; issue prefetch of slice t+1; ONE barrier; then concurrently:
//   waves w/ rtid<160  : H pass raw[t&1] -> hsb[t&1] (9-tap, 5ch, fp16)
//   wave  w/ rtid>=192 : W pass hsb[(t-1)&1] -> 9-tap slide -> fp16x8 ring
//                        -> rolling D-sums -> cc epilogue (8 outputs/thread)
// Race audit: H(t) writes hsb[t&1]; last reader W(t-2) ran before bar(t). ✓
//             S(t) writes raw[t&1]; last reader H(t-2) ran before bar(t-1). ✓
// fp16 ring/hs: rolling add/sub uses identical rounded values -> cancels
// exactly; abs err on D-sums ~0.1 of <=729 -> final mean err ~1e-5 << 5.8e-4.
__global__ __launch_bounds__(256, 2) void kf(const float* __restrict__ I,
                                             const float* __restrict__ J,
                                             float* __restrict__ partial) {
    __shared__ float rawb[2][2][24][40];   // [parity][input][row][col] 15360 B
    __shared__ h4    hsb[2][5][16][10];    // [parity][ch][row][f4col]  12800 B
    __shared__ h8    ring[9][5][64];       // [slot][ch][f8col]         46080 B

    const int tid = threadIdx.x;
    const int bx  = blockIdx.x;
    const int b   = blockIdx.z;
    const int tx  = bx % 5, ty = bx / 5;   // 5 w-tiles x 12 h-tiles
    const int w0 = tx * 32, h0 = ty * 16;
    const int d0 = blockIdx.y * DOUT;
    const int bid = bx + 60 * (blockIdx.y + 4 * b);

    // wave roles; W-wave lands on SIMD3 (even bx) or SIMD1 (odd bx) to avoid
    // doubling both resident blocks' W-waves on one SIMD.
    const int  rtid = tid ^ ((bx & 1) << 7);
    const bool isW  = (rtid >= 192);
    const bool isH  = (rtid < 160);
    const int  p    = rtid & 63;           // W lane: f8-output id
    const int  wr   = p >> 2, wg8 = p & 3; // row, f8-col-group
    const int  hr   = rtid / 10, hk = rtid % 10;   // H task (row, f4col)

    // ---- staging decode: 480 f4-tasks (0..239 I, 240..479 J), stride-40 rows
    const int  uA   = tid;
    const int  qA   = (uA < 240) ? uA : uA - 240;
    const int  inpA = (uA < 240) ? 0 : 1;
    const int  rowA = qA / 10, gA = qA % 10;
    const int  ghA = h0 - 4 + rowA, gwA = w0 - 4 + gA * 4;
    const bool okA = (ghA >= 0 && ghA < HH && gwA >= 0 && gwA < WW);
    const size_t offA = (size_t)ghA * WW + gwA;
    const int  ldsA = inpA * 960 + rowA * 40 + gA * 4;
    const float* srcA = inpA ? J : I;

    const bool hasB = (tid < 224);         // taskB = tid+256 in [256,480) -> J
    const int  qB   = tid + 16;
    const int  rowB = qB / 10, gB = qB % 10;
    const int  ghB = h0 - 4 + rowB, gwB = w0 - 4 + gB * 4;
    const bool okB = hasB && (ghB >= 0 && ghB < HH && gwB >= 0 && gwB < WW);
    const size_t offB = (size_t)ghB * WW + gwB;
    const int  ldsB = 960 + rowB * 40 + gB * 4;

    float* rawF = &rawb[0][0][0][0];
    const size_t base_b = (size_t)b * DD * HWs;

    v4 pA = (v4)0.f, pB = (v4)0.f;
    {   // preload first slice (d0>0; d0==0 starts with ghost slices)
        const int s0 = d0 - 4;
        if (s0 >= 0) {
            const size_t sb = base_b + (size_t)s0 * HWs;
            if (okA) pA = *(const v4*)(srcA + sb + offA);
            if (okB) pB = *(const v4*)(J + sb + offB);
        }
    }

    v8 S[5] = {(v8)0.f, (v8)0.f, (v8)0.f, (v8)0.f, (v8)0.f};
    v8 accv = (v8)0.f;
    int wslot = 0;
    const float inv = 1.0f / 729.0f;

    for (int t = 0; t <= NIT; ++t) {
        const int  si  = d0 - 4 + t;
        const bool sv  = (t < NIT) && (si >= 0 && si < DD);  // block-uniform
        const int  par = t & 1;

        if (sv) {   // stage regs -> raw[par]
            *(v4*)(rawF + par * 1920 + ldsA) = pA;
            if (hasB) *(v4*)(rawF + par * 1920 + ldsB) = pB;
        }
        if (t + 1 < NIT) {   // prefetch slice t+1 (hidden behind H/W phases)
            const int sn = si + 1;
            if (sn >= 0 && sn < DD) {
                const size_t sb = base_b + (size_t)sn * HWs;
                pA = okA ? *(const v4*)(srcA + sb + offA) : (v4)0.f;
                if (hasB) pB = okB ? *(const v4*)(J + sb + offB) : (v4)0.f;
            }
        }
        __syncthreads();     // the ONE barrier per slice

        if (sv && isH) {     // H pass: 9-tap vertical, 5 channels -> fp16
            v4 sI = (v4)0.f, sJ = (v4)0.f, sII = (v4)0.f, sJJ = (v4)0.f,
               sIJ = (v4)0.f;
#pragma unroll
            for (int tt = 0; tt < 9; ++tt) {
                v4 a  = *(const v4*)&rawb[par][0][hr + tt][hk * 4];
                v4 bb = *(const v4*)&rawb[par][1][hr + tt][hk * 4];
                sI += a; sJ += bb; sII += a * a; sJJ += bb * bb; sIJ += a * bb;
            }
            hsb[par][0][hr][hk] = __builtin_convertvector(sI,  h4);
            hsb[par][1][hr][hk] = __builtin_convertvector(sJ,  h4);
            hsb[par][2][hr][hk] = __builtin_convertvector(sII, h4);
            hsb[par][3][hr][hk] = __builtin_convertvector(sJJ, h4);
            hsb[par][4][hr][hk] = __builtin_convertvector(sIJ, h4);
        }

        if (t >= 1 && isW) { // W pass for slice t-1 + ring + rolling D + cc
            const int tp  = t - 1;
            const int sip = d0 - 4 + tp;
            v8 o[5];
            if (sip >= 0 && sip < DD) {
                const int pb = tp & 1;
#pragma unroll
                for (int c = 0; c < 5; ++c) {
                    const h4* hp = &hsb[pb][c][wr][wg8 * 2];
                    v8 fa = __builtin_convertvector(*(const h8*)hp, v8);
                    v8 fb = __builtin_convertvector(*(const h8*)(hp + 2), v8);
                    float s = fa[0] + fa[1] + fa[2] + fa[3] + fa[4] + fa[5] +
                              fa[6] + fa[7] + fb[0];
                    v8 ov; ov[0] = s;
                    s = s - fa[0] + fb[1]; ov[1] = s;
                    s = s - fa[1] + fb[2]; ov[2] = s;
                    s = s - fa[2] + fb[3]; ov[3] = s;
                    s = s - fa[3] + fb[4]; ov[4] = s;
                    s = s - fa[4] + fb[5]; ov[5] = s;
                    s = s - fa[5] + fb[6]; ov[6] = s;
                    s = s - fa[6] + fb[7]; ov[7] = s;
                    o[c] = ov;
                }
            } else {
#pragma unroll
                for (int c = 0; c < 5; ++c) o[c] = (v8)0.f;
            }
#pragma unroll
            for (int c = 0; c < 5; ++c) {
                h8 nv = __builtin_convertvector(o[c], h8);
                if (tp >= 9)
                    S[c] -= __builtin_convertvector(ring[wslot][c][p], v8);
                ring[wslot][c][p] = nv;
                S[c] += __builtin_convertvector(nv, v8);
            }
            if (++wslot == 9) wslot = 0;

            if (tp >= 8) {   // output depth d = d0 + tp - 8
                v8 mu1 = S[0] * inv, mu2 = S[1] * inv;
                v8 g1  = S[2] * inv - mu1 * mu1;
                v8 g2  = S[3] * inv - mu2 * mu2;
                v8 g12 = S[4] * inv - mu1 * mu2;
                v8 num = g12 * g12;
                v8 den = g1 * g2 + 1e-5f;
#pragma unroll
                for (int e = 0; e < 8; ++e)
                    accv[e] += __fdividef(num[e], den[e]);
            }
        }
    }

    // only the W wave holds acc: wave-local shuffle reduce, one store/block
    if (isW) {
        float a = accv[0] + accv[1] + accv[2] + accv[3] +
                  accv[4] + accv[5] + accv[6] + accv[7];
#pragma unroll
        for (int off = 32; off > 0; off >>= 1) a += __shfl_down(a, off);
        if (p == 0) partial[bid] = a;
    }
}

__global__ void k3_final(const float* __restrict__ partial,
                         float* __restrict__ out) {
    __shared__ float r[512];
    const int i = threadIdx.x;
    r[i] = (i < NBLK) ? partial[i] : 0.f;
    __syncthreads();
    for (int off = 256; off > 0; off >>= 1) {
        if (i < off) r[i] += r[i + off];
        __syncthreads();
    }
    if (i == 0) out[0] = -r[0] * (1.0f / NTOT);
}

extern "C" void kernel_launch(void* const* d_in, const int* in_sizes, int n_in,
                              void* d_out, int out_size, void* d_ws, size_t ws_size,
                              hipStream_t stream) {
    (void)in_sizes; (void)n_in; (void)out_size; (void)ws_size;
    const float* I = (const float*)d_in[0];   // y_true
    const float* J = (const float*)d_in[1];   // y_pred
    float* out     = (float*)d_out;
    float* partial = (float*)d_ws;            // NBLK floats, every slot written

    dim3 grid(60, 4, 2);                      // (5w x 12h tiles, D/40, B)
    kf<<<grid, 256, 0, stream>>>(I, J, partial);
    k3_final<<<1, 512, 0, stream>>>(partial, out);
}